// Round 1
// baseline (1235.526 us; speedup 1.0000x reference)
//
#include <hip/hip_runtime.h>
#include <stdint.h>

#define N 8192
#define D 256
#define D4 (D / 4)

#define BI 32            // rows per mining tile
#define BJX 64           // cols per inner tile (== one column per tx lane)
#define COLSPLIT 4       // blocks along the column dimension
#define ROWTILES (N / BI)            // 256
#define JCHUNK (N / COLSPLIT)        // 2048
#define MARGIN 1.0f
#define EPS 1e-6f

// ---------------- ws layout ----------------
// u64 posP[N]; u64 negP[N]; float sq[N]; float lossSum; unsigned cnt;

__global__ void k_init(unsigned long long* posP, unsigned long long* negP,
                       float* lossSum, unsigned int* cnt) {
    int idx = blockIdx.x * blockDim.x + threadIdx.x;
    if (idx < N) {
        posP[idx] = 0ull;
        negP[idx] = ~0ull;
    }
    if (idx == 0) {
        *lossSum = 0.0f;
        *cnt = 0u;
    }
}

__global__ void k_sq(const float* __restrict__ emb, float* __restrict__ sq) {
    int wave = threadIdx.x >> 6;
    int lane = threadIdx.x & 63;
    int row = blockIdx.x * 4 + wave;
    const float4* e4 = (const float4*)(emb + (size_t)row * D);
    float4 v = e4[lane];
    float s = v.x * v.x + v.y * v.y + v.z * v.z + v.w * v.w;
    #pragma unroll
    for (int o = 32; o; o >>= 1) s += __shfl_xor(s, o, 64);
    if (lane == 0) sq[row] = s;
}

__global__ __launch_bounds__(256) void k_mine(
        const float* __restrict__ emb,
        const int* __restrict__ labels, const int* __restrict__ sbj,
        const float* __restrict__ sq,
        unsigned long long* __restrict__ posP,
        unsigned long long* __restrict__ negP) {
    __shared__ __align__(16) float As[BI][D + 4];   // stride 260 floats (16B-aligned rows)
    __shared__ int labA[BI];
    __shared__ int sbjA[BI];
    __shared__ float sqA[BI];
    __shared__ unsigned long long lbpS[BI];
    __shared__ unsigned long long lbnS[BI];

    int tid = threadIdx.x;
    int tx = tid & 63;            // column lane within tile; also: wave = ty
    int ty = tid >> 6;            // 0..3 (one wave per ty)
    int rowTile = blockIdx.x & (ROWTILES - 1);
    int colPart = blockIdx.x >> 8;     // blockIdx.x / ROWTILES
    int i0 = rowTile * BI;
    int j0 = colPart * JCHUNK;

    // ---- load A strip (32 x 256 fp32) into LDS, coalesced float4 ----
    {
        const float4* g = (const float4*)(emb + (size_t)i0 * D);
        #pragma unroll
        for (int it = 0; it < 8; ++it) {
            int f4 = tid + it * 256;
            int r = f4 >> 6;
            int k4 = f4 & 63;
            float4 v = g[r * D4 + k4];
            *(float4*)&As[r][k4 * 4] = v;
        }
        if (tid < BI) {
            labA[tid] = labels[i0 + tid];
            sbjA[tid] = sbj[i0 + tid];
            sqA[tid]  = sq[i0 + tid];
            lbpS[tid] = 0ull;
            lbnS[tid] = ~0ull;
        }
    }
    __syncthreads();

    unsigned long long lbp[8], lbn[8];
    #pragma unroll
    for (int m = 0; m < 8; ++m) { lbp[m] = 0ull; lbn[m] = ~0ull; }

    int baseRow = ty * 8;

    for (int jt = 0; jt < JCHUNK; jt += BJX) {
        int j = j0 + jt + tx;
        const float4* bcol = (const float4*)(emb + (size_t)j * D);
        float acc[8];
        #pragma unroll
        for (int m = 0; m < 8; ++m) acc[m] = 0.0f;

        for (int k4 = 0; k4 < D4; ++k4) {
            float4 b = bcol[k4];
            #pragma unroll
            for (int m = 0; m < 8; ++m) {
                float4 a = *(const float4*)&As[baseRow + m][k4 * 4];
                acc[m] += a.x * b.x + a.y * b.y + a.z * b.z + a.w * b.w;
            }
        }

        int labj = labels[j];
        int sbjj = sbj[j];
        float sqj = sq[j];
        #pragma unroll
        for (int m = 0; m < 8; ++m) {
            int r = baseRow + m;
            int i = i0 + r;
            float d2 = fmaxf(sqA[r] + sqj - 2.0f * acc[m], 0.0f);
            unsigned long long db = ((unsigned long long)__float_as_uint(d2)) << 32;
            bool ss = (sbjj == sbjA[r]);
            bool sl = (labj == labA[r]);
            if (ss && sl && (j != i)) {
                unsigned long long p = db | (unsigned long long)(unsigned)(~(unsigned)j);
                if (p > lbp[m]) lbp[m] = p;
            }
            if (ss && !sl) {
                unsigned long long q = db | (unsigned long long)(unsigned)j;
                if (q < lbn[m]) lbn[m] = q;
            }
        }
    }

    // ---- merge per-thread bests into block-level LDS, then global ----
    #pragma unroll
    for (int m = 0; m < 8; ++m) {
        atomicMax(&lbpS[baseRow + m], lbp[m]);
        atomicMin(&lbnS[baseRow + m], lbn[m]);
    }
    __syncthreads();
    if (tid < BI) {
        atomicMax(&posP[i0 + tid], lbpS[tid]);
        atomicMin(&negP[i0 + tid], lbnS[tid]);
    }
}

__global__ void k_fin(const float* __restrict__ emb,
                      const unsigned long long* __restrict__ posP,
                      const unsigned long long* __restrict__ negP,
                      float* lossSum, unsigned int* cnt) {
    int wave = threadIdx.x >> 6;
    int lane = threadIdx.x & 63;
    int i = blockIdx.x * 4 + wave;
    unsigned long long p = posP[i];
    unsigned long long nn = negP[i];
    bool valid = (p != 0ull) && (nn != ~0ull);
    if (!valid) return;  // wave-uniform branch (all lanes share i)
    int hp = (int)(~(unsigned)(p & 0xffffffffull));
    int hn = (int)(unsigned)(nn & 0xffffffffull);
    const float4* a  = (const float4*)(emb + (size_t)i  * D);
    const float4* bp = (const float4*)(emb + (size_t)hp * D);
    const float4* bn = (const float4*)(emb + (size_t)hn * D);
    float4 va = a[lane], vp = bp[lane], vn = bn[lane];
    float x, sp = 0.0f, sn = 0.0f;
    x = va.x - vp.x + EPS; sp += x * x;
    x = va.y - vp.y + EPS; sp += x * x;
    x = va.z - vp.z + EPS; sp += x * x;
    x = va.w - vp.w + EPS; sp += x * x;
    x = va.x - vn.x + EPS; sn += x * x;
    x = va.y - vn.y + EPS; sn += x * x;
    x = va.z - vn.z + EPS; sn += x * x;
    x = va.w - vn.w + EPS; sn += x * x;
    #pragma unroll
    for (int o = 32; o; o >>= 1) {
        sp += __shfl_xor(sp, o, 64);
        sn += __shfl_xor(sn, o, 64);
    }
    if (lane == 0) {
        float per = fmaxf(sqrtf(sp) - sqrtf(sn) + MARGIN, 0.0f);
        atomicAdd(lossSum, per);
        atomicAdd(cnt, 1u);
    }
}

__global__ void k_out(const float* lossSum, const unsigned int* cnt, float* out) {
    unsigned c = *cnt;
    out[0] = *lossSum / (float)(c > 0u ? c : 1u);
}

extern "C" void kernel_launch(void* const* d_in, const int* in_sizes, int n_in,
                              void* d_out, int out_size, void* d_ws, size_t ws_size,
                              hipStream_t stream) {
    const float* emb  = (const float*)d_in[0];
    const int* labels = (const int*)d_in[1];
    const int* sbjv   = (const int*)d_in[2];
    float* out = (float*)d_out;

    unsigned long long* posP = (unsigned long long*)d_ws;
    unsigned long long* negP = posP + N;
    float* sq = (float*)(negP + N);
    float* lossSum = sq + N;
    unsigned int* cnt = (unsigned int*)(lossSum + 1);

    k_init<<<N / 256, 256, 0, stream>>>(posP, negP, lossSum, cnt);
    k_sq<<<N / 4, 256, 0, stream>>>(emb, sq);
    k_mine<<<ROWTILES * COLSPLIT, 256, 0, stream>>>(emb, labels, sbjv, sq, posP, negP);
    k_fin<<<N / 4, 256, 0, stream>>>(emb, posP, negP, lossSum, cnt);
    k_out<<<1, 1, 0, stream>>>(lossSum, cnt, out);
}

// Round 2
// 375.630 us; speedup vs baseline: 3.2892x; 3.2892x over previous
//
#include <hip/hip_runtime.h>
#include <stdint.h>

#define N 8192
#define D 256
#define NSUBJ 16
#define PADS 768                 // padded slot per subject (mean 512, +11 sigma safe)
#define GN (NSUBJ * PADS)        // 12288 gathered rows
#define TPS 6                    // 128-row tiles per subject dim (6*128 = 768)
#define MARGIN 1.0f
#define EPS 1e-6f

typedef __attribute__((ext_vector_type(8))) short short8;   // 8 bf16 = 4 VGPRs (MFMA A/B frag)
typedef __attribute__((ext_vector_type(4))) float f32x4;    // MFMA C/D frag
typedef __attribute__((ext_vector_type(4))) unsigned short us4;
typedef unsigned long long u64;
typedef unsigned int __attribute__((address_space(1))) as1_uint;
typedef unsigned int __attribute__((address_space(3))) as3_uint;

__device__ __forceinline__ void gl_lds16(const unsigned short* g, unsigned short* l) {
    // async global->LDS, 16B/lane; LDS dest = wave-uniform base + lane*16
    __builtin_amdgcn_global_load_lds((const as1_uint*)g, (as3_uint*)l, 16, 0, 0);
}

__device__ __forceinline__ unsigned short f2bf(float x) {
    unsigned u = __float_as_uint(x);
    u += 0x7fffu + ((u >> 16) & 1u);
    return (unsigned short)(u >> 16);
}

// ---------------- ws layout ----------------
// ushort gH[GN*D]; u64 posP[GN]; u64 negP[GN]; int gIdx[GN]; int gLab[GN];
// float gSq[GN]; int writePtr[16]; float lossSum; uint cnt;

__global__ void k_init(u64* posP, u64* negP, int* gIdx, int* gLab,
                       int* writePtr, float* lossSum, unsigned int* cnt) {
    int idx = blockIdx.x * blockDim.x + threadIdx.x;
    if (idx < GN) {
        posP[idx] = 0ull;
        negP[idx] = ~0ull;
        gIdx[idx] = -1;
        gLab[idx] = -2;
    }
    if (idx < NSUBJ) writePtr[idx] = idx * PADS;
    if (idx == 0) { *lossSum = 0.0f; *cnt = 0u; }
}

// gather rows by subject into padded slots; fp32 -> bf16; fold in sq-norm
__global__ void k_scatter(const float* __restrict__ emb, const int* __restrict__ labels,
                          const int* __restrict__ sbjv,
                          unsigned short* __restrict__ gH, int* __restrict__ gIdx,
                          int* __restrict__ gLab, float* __restrict__ gSq,
                          int* __restrict__ writePtr) {
    int wave = threadIdx.x >> 6;
    int lane = threadIdx.x & 63;
    int row = blockIdx.x * 4 + wave;
    const float4* e4 = (const float4*)(emb + (size_t)row * D);
    float4 v = e4[lane];
    float s = v.x * v.x + v.y * v.y + v.z * v.z + v.w * v.w;
    #pragma unroll
    for (int o = 32; o; o >>= 1) s += __shfl_xor(s, o, 64);
    int p = 0;
    if (lane == 0) p = atomicAdd(&writePtr[sbjv[row]], 1);
    p = __shfl(p, 0, 64);
    us4 h;
    h.x = f2bf(v.x); h.y = f2bf(v.y); h.z = f2bf(v.z); h.w = f2bf(v.w);
    *(us4*)(gH + (size_t)p * D + lane * 4) = h;
    if (lane == 0) { gIdx[p] = row; gLab[p] = labels[row]; gSq[p] = s; }
}

// block-diagonal bf16 MFMA GEMM + fused hardest-pos/neg mining
__global__ __launch_bounds__(256) void k_mine(
        const unsigned short* __restrict__ gH, const int* __restrict__ gIdx,
        const int* __restrict__ gLab, const float* __restrict__ gSq,
        const int* __restrict__ writePtr,
        u64* __restrict__ posP, u64* __restrict__ negP) {
    __shared__ unsigned short As[128 * 32];   // 8 KB, row-major [row][k] (BK=32)
    __shared__ unsigned short Bs[128 * 32];   // 8 KB
    __shared__ int labA[128], idxA[128], labB[128], idxB[128];
    __shared__ float sqA[128], sqB[128];

    int s  = blockIdx.x / (TPS * TPS);
    int t  = blockIdx.x % (TPS * TPS);
    int rt = t / TPS, ct = t % TPS;
    int base = s * PADS;
    int cntS = writePtr[s] - base;
    if (rt * 128 >= cntS || ct * 128 >= cntS) return;   // uniform: whole tile is pad
    int i0 = base + rt * 128;
    int j0 = base + ct * 128;

    int tid  = threadIdx.x;
    int lane = tid & 63, w = tid >> 6;
    int quad = lane >> 4, l15 = lane & 15;
    int wRow = (w & 1) * 64, wCol = (w >> 1) * 64;   // wave tile 64x64

    if (tid < 128) {
        labA[tid] = gLab[i0 + tid]; idxA[tid] = gIdx[i0 + tid]; sqA[tid] = gSq[i0 + tid];
    } else {
        int c = tid - 128;
        labB[c] = gLab[j0 + c]; idxB[c] = gIdx[j0 + c]; sqB[c] = gSq[j0 + c];
    }

    f32x4 acc[4][4];
    #pragma unroll
    for (int mt = 0; mt < 4; ++mt)
        #pragma unroll
        for (int nt = 0; nt < 4; ++nt) {
            f32x4 z = {0.f, 0.f, 0.f, 0.f};
            acc[mt][nt] = z;
        }

    for (int kb = 0; kb < 8; ++kb) {          // K = 8 * 32
        int k0 = kb * 32;
        #pragma unroll
        for (int rr = 0; rr < 2; ++rr) {      // 128 rows x 64B = 2 rounds of 256x16B
            int f = rr * 256 + tid;
            int row = f >> 2, seg = f & 3;
            unsigned short* ldst = (unsigned short*)&As[0] + (size_t)(rr * 256 + w * 64) * 8;
            gl_lds16(gH + (size_t)(i0 + row) * D + k0 + seg * 8, ldst);
            unsigned short* ldstB = (unsigned short*)&Bs[0] + (size_t)(rr * 256 + w * 64) * 8;
            gl_lds16(gH + (size_t)(j0 + row) * D + k0 + seg * 8, ldstB);
        }
        __syncthreads();
        short8 a[4], b[4];
        int koff = quad * 8;
        #pragma unroll
        for (int mt = 0; mt < 4; ++mt)
            a[mt] = *(const short8*)(As + (wRow + mt * 16 + l15) * 32 + koff);
        #pragma unroll
        for (int nt = 0; nt < 4; ++nt)
            b[nt] = *(const short8*)(Bs + (wCol + nt * 16 + l15) * 32 + koff);
        #pragma unroll
        for (int mt = 0; mt < 4; ++mt)
            #pragma unroll
            for (int nt = 0; nt < 4; ++nt)
                acc[mt][nt] = __builtin_amdgcn_mfma_f32_16x16x32_bf16(
                    a[mt], b[nt], acc[mt][nt], 0, 0, 0);
        __syncthreads();
    }

    // ---- mining epilogue: C layout col = lane&15, row = quad*4 + reg ----
    #pragma unroll
    for (int mt = 0; mt < 4; ++mt) {
        u64 bp[4], bn[4];
        int rloc[4], labr[4], idxr[4];
        float sqr[4];
        #pragma unroll
        for (int rg = 0; rg < 4; ++rg) {
            int r = wRow + mt * 16 + quad * 4 + rg;
            rloc[rg] = r; labr[rg] = labA[r]; idxr[rg] = idxA[r]; sqr[rg] = sqA[r];
            bp[rg] = 0ull; bn[rg] = ~0ull;
        }
        #pragma unroll
        for (int nt = 0; nt < 4; ++nt) {
            int c = wCol + nt * 16 + l15;
            int labc = labB[c], idxc = idxB[c];
            float sqc = sqB[c];
            f32x4 v = acc[mt][nt];
            #pragma unroll
            for (int rg = 0; rg < 4; ++rg) {
                float d2 = fmaxf(sqr[rg] + sqc - 2.0f * v[rg], 0.0f);
                u64 db = ((u64)__float_as_uint(d2)) << 32;
                if (labc == labr[rg] && idxc != idxr[rg] && idxc >= 0) {
                    u64 pk = db | (u64)(unsigned)(~(unsigned)idxc);
                    if (pk > bp[rg]) bp[rg] = pk;
                }
                if (labc != labr[rg] && idxc >= 0) {
                    u64 nk = db | (u64)(unsigned)idxc;
                    if (nk < bn[rg]) bn[rg] = nk;
                }
            }
        }
        #pragma unroll
        for (int o = 1; o < 16; o <<= 1) {
            #pragma unroll
            for (int rg = 0; rg < 4; ++rg) {
                u64 pp = __shfl_xor(bp[rg], o, 64);
                if (pp > bp[rg]) bp[rg] = pp;
                u64 qq = __shfl_xor(bn[rg], o, 64);
                if (qq < bn[rg]) bn[rg] = qq;
            }
        }
        if (l15 == 0) {
            #pragma unroll
            for (int rg = 0; rg < 4; ++rg) {
                if (bp[rg]) atomicMax(&posP[i0 + rloc[rg]], bp[rg]);
                if (bn[rg] != ~0ull) atomicMin(&negP[i0 + rloc[rg]], bn[rg]);
            }
        }
    }
}

__global__ void k_fin(const float* __restrict__ emb, const int* __restrict__ gIdx,
                      const u64* __restrict__ posP, const u64* __restrict__ negP,
                      float* lossSum, unsigned int* cnt) {
    int wave = threadIdx.x >> 6;
    int lane = threadIdx.x & 63;
    int r = blockIdx.x * 4 + wave;
    int i = gIdx[r];
    u64 p = posP[r];
    u64 nn = negP[r];
    bool valid = (i >= 0) && (p != 0ull) && (nn != ~0ull);
    if (!valid) return;  // wave-uniform
    int hp = (int)(~(unsigned)(p & 0xffffffffull));
    int hn = (int)(unsigned)(nn & 0xffffffffull);
    const float4* a  = (const float4*)(emb + (size_t)i  * D);
    const float4* bp = (const float4*)(emb + (size_t)hp * D);
    const float4* bn = (const float4*)(emb + (size_t)hn * D);
    float4 va = a[lane], vp = bp[lane], vn = bn[lane];
    float x, sp = 0.0f, sn = 0.0f;
    x = va.x - vp.x + EPS; sp += x * x;
    x = va.y - vp.y + EPS; sp += x * x;
    x = va.z - vp.z + EPS; sp += x * x;
    x = va.w - vp.w + EPS; sp += x * x;
    x = va.x - vn.x + EPS; sn += x * x;
    x = va.y - vn.y + EPS; sn += x * x;
    x = va.z - vn.z + EPS; sn += x * x;
    x = va.w - vn.w + EPS; sn += x * x;
    #pragma unroll
    for (int o = 32; o; o >>= 1) {
        sp += __shfl_xor(sp, o, 64);
        sn += __shfl_xor(sn, o, 64);
    }
    if (lane == 0) {
        float per = fmaxf(sqrtf(sp) - sqrtf(sn) + MARGIN, 0.0f);
        atomicAdd(lossSum, per);
        atomicAdd(cnt, 1u);
    }
}

__global__ void k_out(const float* lossSum, const unsigned int* cnt, float* out) {
    unsigned c = *cnt;
    out[0] = *lossSum / (float)(c > 0u ? c : 1u);
}

extern "C" void kernel_launch(void* const* d_in, const int* in_sizes, int n_in,
                              void* d_out, int out_size, void* d_ws, size_t ws_size,
                              hipStream_t stream) {
    const float* emb  = (const float*)d_in[0];
    const int* labels = (const int*)d_in[1];
    const int* sbjv   = (const int*)d_in[2];
    float* out = (float*)d_out;

    char* ws = (char*)d_ws;
    unsigned short* gH = (unsigned short*)ws;                 // GN*D*2 = 6291456 B
    u64* posP = (u64*)(ws + 6291456);                         // GN*8
    u64* negP = (u64*)(ws + 6291456 + 98304);
    int* gIdx = (int*)(ws + 6291456 + 196608);                // GN*4
    int* gLab = (int*)(ws + 6291456 + 245760);
    float* gSq = (float*)(ws + 6291456 + 294912);
    int* writePtr = (int*)(ws + 6291456 + 344064);
    float* lossSum = (float*)(ws + 6291456 + 344064 + 64);
    unsigned int* cnt = (unsigned int*)(ws + 6291456 + 344064 + 68);

    k_init<<<(GN + 255) / 256, 256, 0, stream>>>(posP, negP, gIdx, gLab, writePtr, lossSum, cnt);
    k_scatter<<<N / 4, 256, 0, stream>>>(emb, labels, sbjv, gH, gIdx, gLab, gSq, writePtr);
    k_mine<<<NSUBJ * TPS * TPS, 256, 0, stream>>>(gH, gIdx, gLab, gSq, writePtr, posP, negP);
    k_fin<<<GN / 4, 256, 0, stream>>>(emb, gIdx, posP, negP, lossSum, cnt);
    k_out<<<1, 1, 0, stream>>>(lossSum, cnt, out);
}

// Round 3
// 188.263 us; speedup vs baseline: 6.5628x; 1.9952x over previous
//
#include <hip/hip_runtime.h>
#include <stdint.h>

#define N 8192
#define D 256
#define NSUBJ 16
#define PADS 768                 // padded slot per subject (mean 512, +11 sigma safe)
#define GN (NSUBJ * PADS)        // 12288 gathered rows
#define TPS 6                    // 128-row tiles per subject dim (6*128 = 768)
#define MARGIN 1.0f
#define EPS 1e-6f

typedef __attribute__((ext_vector_type(8))) short short8;   // 8 bf16 = 4 VGPRs (MFMA A/B frag)
typedef __attribute__((ext_vector_type(4))) float f32x4;    // MFMA C/D frag
typedef __attribute__((ext_vector_type(4))) unsigned short us4;
typedef unsigned long long u64;
typedef unsigned int __attribute__((address_space(1))) as1_uint;
typedef unsigned int __attribute__((address_space(3))) as3_uint;

__device__ __forceinline__ void gl_lds16(const unsigned short* g, unsigned short* l) {
    // async global->LDS, 16B/lane; LDS dest = wave-uniform base + lane*16
    __builtin_amdgcn_global_load_lds((const as1_uint*)g, (as3_uint*)l, 16, 0, 0);
}

__device__ __forceinline__ unsigned short f2bf(float x) {
    unsigned u = __float_as_uint(x);
    u += 0x7fffu + ((u >> 16) & 1u);
    return (unsigned short)(u >> 16);
}

// ---------------- ws layout ----------------
// ushort gH[GN*D]; u64 posP[GN]; u64 negP[GN]; int gIdx[GN]; int gLab[GN];
// float gSq[GN]; int writePtr[16] (+pad to 64B); float2 perOut[GN];

__global__ void k_init(u64* posP, u64* negP, int* gIdx, int* gLab, int* writePtr) {
    int idx = blockIdx.x * blockDim.x + threadIdx.x;
    if (idx < GN) {
        posP[idx] = 0ull;
        negP[idx] = ~0ull;
        gIdx[idx] = -1;
        gLab[idx] = -2;
    }
    if (idx < NSUBJ) writePtr[idx] = idx * PADS;
}

// gather rows by subject into padded slots; fp32 -> bf16; fold in sq-norm
__global__ void k_scatter(const float* __restrict__ emb, const int* __restrict__ labels,
                          const int* __restrict__ sbjv,
                          unsigned short* __restrict__ gH, int* __restrict__ gIdx,
                          int* __restrict__ gLab, float* __restrict__ gSq,
                          int* __restrict__ writePtr) {
    int wave = threadIdx.x >> 6;
    int lane = threadIdx.x & 63;
    int row = blockIdx.x * 4 + wave;
    const float4* e4 = (const float4*)(emb + (size_t)row * D);
    float4 v = e4[lane];
    float s = v.x * v.x + v.y * v.y + v.z * v.z + v.w * v.w;
    #pragma unroll
    for (int o = 32; o; o >>= 1) s += __shfl_xor(s, o, 64);
    int p = 0;
    if (lane == 0) p = atomicAdd(&writePtr[sbjv[row]], 1);
    p = __shfl(p, 0, 64);
    us4 h;
    h.x = f2bf(v.x); h.y = f2bf(v.y); h.z = f2bf(v.z); h.w = f2bf(v.w);
    *(us4*)(gH + (size_t)p * D + lane * 4) = h;
    if (lane == 0) { gIdx[p] = row; gLab[p] = labels[row]; gSq[p] = s; }
}

// block-diagonal bf16 MFMA GEMM + fused hardest-pos/neg mining
__global__ __launch_bounds__(256) void k_mine(
        const unsigned short* __restrict__ gH, const int* __restrict__ gIdx,
        const int* __restrict__ gLab, const float* __restrict__ gSq,
        const int* __restrict__ writePtr,
        u64* __restrict__ posP, u64* __restrict__ negP) {
    __shared__ unsigned short As[128 * 32];   // 8 KB, row-major [row][k] (BK=32)
    __shared__ unsigned short Bs[128 * 32];   // 8 KB
    __shared__ int labA[128], idxA[128], labB[128], idxB[128];
    __shared__ float sqA[128], sqB[128];

    int s  = blockIdx.x / (TPS * TPS);
    int t  = blockIdx.x % (TPS * TPS);
    int rt = t / TPS, ct = t % TPS;
    int base = s * PADS;
    int cntS = writePtr[s] - base;
    if (rt * 128 >= cntS || ct * 128 >= cntS) return;   // uniform: whole tile is pad
    int i0 = base + rt * 128;
    int j0 = base + ct * 128;

    int tid  = threadIdx.x;
    int lane = tid & 63, w = tid >> 6;
    int quad = lane >> 4, l15 = lane & 15;
    int wRow = (w & 1) * 64, wCol = (w >> 1) * 64;   // wave tile 64x64

    if (tid < 128) {
        labA[tid] = gLab[i0 + tid]; idxA[tid] = gIdx[i0 + tid]; sqA[tid] = gSq[i0 + tid];
    } else {
        int c = tid - 128;
        labB[c] = gLab[j0 + c]; idxB[c] = gIdx[j0 + c]; sqB[c] = gSq[j0 + c];
    }

    f32x4 acc[4][4];
    #pragma unroll
    for (int mt = 0; mt < 4; ++mt)
        #pragma unroll
        for (int nt = 0; nt < 4; ++nt) {
            f32x4 z = {0.f, 0.f, 0.f, 0.f};
            acc[mt][nt] = z;
        }

    for (int kb = 0; kb < 8; ++kb) {          // K = 8 * 32
        int k0 = kb * 32;
        #pragma unroll
        for (int rr = 0; rr < 2; ++rr) {      // 128 rows x 64B = 2 rounds of 256x16B
            int f = rr * 256 + tid;
            int row = f >> 2, seg = f & 3;
            unsigned short* ldst = (unsigned short*)&As[0] + (size_t)(rr * 256 + w * 64) * 8;
            gl_lds16(gH + (size_t)(i0 + row) * D + k0 + seg * 8, ldst);
            unsigned short* ldstB = (unsigned short*)&Bs[0] + (size_t)(rr * 256 + w * 64) * 8;
            gl_lds16(gH + (size_t)(j0 + row) * D + k0 + seg * 8, ldstB);
        }
        __syncthreads();
        short8 a[4], b[4];
        int koff = quad * 8;
        #pragma unroll
        for (int mt = 0; mt < 4; ++mt)
            a[mt] = *(const short8*)(As + (wRow + mt * 16 + l15) * 32 + koff);
        #pragma unroll
        for (int nt = 0; nt < 4; ++nt)
            b[nt] = *(const short8*)(Bs + (wCol + nt * 16 + l15) * 32 + koff);
        #pragma unroll
        for (int mt = 0; mt < 4; ++mt)
            #pragma unroll
            for (int nt = 0; nt < 4; ++nt)
                acc[mt][nt] = __builtin_amdgcn_mfma_f32_16x16x32_bf16(
                    a[mt], b[nt], acc[mt][nt], 0, 0, 0);
        __syncthreads();
    }

    // ---- mining epilogue: C layout col = lane&15, row = quad*4 + reg ----
    #pragma unroll
    for (int mt = 0; mt < 4; ++mt) {
        u64 bp[4], bn[4];
        int rloc[4], labr[4], idxr[4];
        float sqr[4];
        #pragma unroll
        for (int rg = 0; rg < 4; ++rg) {
            int r = wRow + mt * 16 + quad * 4 + rg;
            rloc[rg] = r; labr[rg] = labA[r]; idxr[rg] = idxA[r]; sqr[rg] = sqA[r];
            bp[rg] = 0ull; bn[rg] = ~0ull;
        }
        #pragma unroll
        for (int nt = 0; nt < 4; ++nt) {
            int c = wCol + nt * 16 + l15;
            int labc = labB[c], idxc = idxB[c];
            float sqc = sqB[c];
            f32x4 v = acc[mt][nt];
            #pragma unroll
            for (int rg = 0; rg < 4; ++rg) {
                float d2 = fmaxf(sqr[rg] + sqc - 2.0f * v[rg], 0.0f);
                u64 db = ((u64)__float_as_uint(d2)) << 32;
                if (labc == labr[rg] && idxc != idxr[rg] && idxc >= 0) {
                    u64 pk = db | (u64)(unsigned)(~(unsigned)idxc);
                    if (pk > bp[rg]) bp[rg] = pk;
                }
                if (labc != labr[rg] && idxc >= 0) {
                    u64 nk = db | (u64)(unsigned)idxc;
                    if (nk < bn[rg]) bn[rg] = nk;
                }
            }
        }
        #pragma unroll
        for (int o = 1; o < 16; o <<= 1) {
            #pragma unroll
            for (int rg = 0; rg < 4; ++rg) {
                u64 pp = __shfl_xor(bp[rg], o, 64);
                if (pp > bp[rg]) bp[rg] = pp;
                u64 qq = __shfl_xor(bn[rg], o, 64);
                if (qq < bn[rg]) bn[rg] = qq;
            }
        }
        if (l15 == 0) {
            #pragma unroll
            for (int rg = 0; rg < 4; ++rg) {
                if (bp[rg]) atomicMax(&posP[i0 + rloc[rg]], bp[rg]);
                if (bn[rg] != ~0ull) atomicMin(&negP[i0 + rloc[rg]], bn[rg]);
            }
        }
    }
}

// per-row hinge recompute in fp32; NO global atomics — per-row float2 store
__global__ void k_fin(const float* __restrict__ emb, const int* __restrict__ gIdx,
                      const u64* __restrict__ posP, const u64* __restrict__ negP,
                      float2* __restrict__ perOut) {
    int wave = threadIdx.x >> 6;
    int lane = threadIdx.x & 63;
    int r = blockIdx.x * 4 + wave;
    int i = gIdx[r];
    u64 p = posP[r];
    u64 nn = negP[r];
    bool valid = (i >= 0) && (p != 0ull) && (nn != ~0ull);
    if (!valid) {                         // wave-uniform
        if (lane == 0) perOut[r] = make_float2(0.0f, 0.0f);
        return;
    }
    int hp = (int)(~(unsigned)(p & 0xffffffffull));
    int hn = (int)(unsigned)(nn & 0xffffffffull);
    const float4* a  = (const float4*)(emb + (size_t)i  * D);
    const float4* bp = (const float4*)(emb + (size_t)hp * D);
    const float4* bn = (const float4*)(emb + (size_t)hn * D);
    float4 va = a[lane], vp = bp[lane], vn = bn[lane];
    float x, sp = 0.0f, sn = 0.0f;
    x = va.x - vp.x + EPS; sp += x * x;
    x = va.y - vp.y + EPS; sp += x * x;
    x = va.z - vp.z + EPS; sp += x * x;
    x = va.w - vp.w + EPS; sp += x * x;
    x = va.x - vn.x + EPS; sn += x * x;
    x = va.y - vn.y + EPS; sn += x * x;
    x = va.z - vn.z + EPS; sn += x * x;
    x = va.w - vn.w + EPS; sn += x * x;
    #pragma unroll
    for (int o = 32; o; o >>= 1) {
        sp += __shfl_xor(sp, o, 64);
        sn += __shfl_xor(sn, o, 64);
    }
    if (lane == 0) {
        float per = fmaxf(sqrtf(sp) - sqrtf(sn) + MARGIN, 0.0f);
        perOut[r] = make_float2(per, 1.0f);
    }
}

// single-block tree reduction over perOut, writes final scalar
__global__ void k_reduce(const float4* __restrict__ perOut, float* __restrict__ out) {
    int tid = threadIdx.x;
    float s = 0.0f, c = 0.0f;
    for (int i = tid; i < GN / 2; i += 256) {   // each float4 = 2 (per, valid) pairs
        float4 v = perOut[i];
        s += v.x + v.z;
        c += v.y + v.w;
    }
    #pragma unroll
    for (int o = 32; o; o >>= 1) {
        s += __shfl_xor(s, o, 64);
        c += __shfl_xor(c, o, 64);
    }
    __shared__ float ss[4], sc[4];
    int w = tid >> 6, lane = tid & 63;
    if (lane == 0) { ss[w] = s; sc[w] = c; }
    __syncthreads();
    if (tid == 0) {
        float S = ss[0] + ss[1] + ss[2] + ss[3];
        float C = sc[0] + sc[1] + sc[2] + sc[3];
        out[0] = S / (C < 1.0f ? 1.0f : C);
    }
}

extern "C" void kernel_launch(void* const* d_in, const int* in_sizes, int n_in,
                              void* d_out, int out_size, void* d_ws, size_t ws_size,
                              hipStream_t stream) {
    const float* emb  = (const float*)d_in[0];
    const int* labels = (const int*)d_in[1];
    const int* sbjv   = (const int*)d_in[2];
    float* out = (float*)d_out;

    char* ws = (char*)d_ws;
    unsigned short* gH = (unsigned short*)ws;                 // GN*D*2 = 6291456 B
    u64* posP = (u64*)(ws + 6291456);                         // GN*8 = 98304
    u64* negP = (u64*)(ws + 6291456 + 98304);
    int* gIdx = (int*)(ws + 6291456 + 196608);                // GN*4 = 49152
    int* gLab = (int*)(ws + 6291456 + 245760);
    float* gSq = (float*)(ws + 6291456 + 294912);
    int* writePtr = (int*)(ws + 6291456 + 344064);            // 64 B
    float2* perOut = (float2*)(ws + 6291456 + 344064 + 64);   // GN*8 = 98304

    k_init<<<(GN + 255) / 256, 256, 0, stream>>>(posP, negP, gIdx, gLab, writePtr);
    k_scatter<<<N / 4, 256, 0, stream>>>(emb, labels, sbjv, gH, gIdx, gLab, gSq, writePtr);
    k_mine<<<NSUBJ * TPS * TPS, 256, 0, stream>>>(gH, gIdx, gLab, gSq, writePtr, posP, negP);
    k_fin<<<GN / 4, 256, 0, stream>>>(emb, gIdx, posP, negP, perOut);
    k_reduce<<<1, 256, 0, stream>>>((const float4*)perOut, out);
}

// Round 4
// 111.129 us; speedup vs baseline: 11.1179x; 1.6941x over previous
//
#include <hip/hip_runtime.h>
#include <stdint.h>

#define N 8192
#define D 256
#define NSUBJ 16
#define PADS 768                 // padded slot per subject (mean 512, +11 sigma safe)
#define GN (NSUBJ * PADS)        // 12288 gathered rows
#define TPS 6                    // 128-row tiles per subject dim (6*128 = 768)
#define MARGIN 1.0f
#define EPS 1e-6f

typedef __attribute__((ext_vector_type(8))) short short8;   // 8 bf16 = 4 VGPRs (MFMA A/B frag)
typedef __attribute__((ext_vector_type(4))) float f32x4;    // MFMA C/D frag
typedef __attribute__((ext_vector_type(4))) unsigned short us4;
typedef unsigned long long u64;
typedef unsigned int __attribute__((address_space(1))) as1_uint;
typedef unsigned int __attribute__((address_space(3))) as3_uint;

__device__ __forceinline__ void gl_lds16(const unsigned short* g, unsigned short* l) {
    // async global->LDS, 16B/lane; LDS dest = wave-uniform base + lane*16
    __builtin_amdgcn_global_load_lds((const as1_uint*)g, (as3_uint*)l, 16, 0, 0);
}

__device__ __forceinline__ unsigned short f2bf(float x) {
    unsigned u = __float_as_uint(x);
    u += 0x7fffu + ((u >> 16) & 1u);
    return (unsigned short)(u >> 16);
}

// ---------------- ws layout ----------------
// ushort gH[GN*D]; u64 posP[GN]; u64 negP[GN]; int gIdx[GN]; int gLab[GN];
// float gSq[GN]; int writePtr[16] (+pad to 64B); float2 perOut[GN]; int pos[N];

__global__ void k_init(u64* posP, u64* negP, int* gIdx, int* gLab) {
    int idx = blockIdx.x * blockDim.x + threadIdx.x;
    if (idx < GN) {
        posP[idx] = 0ull;
        negP[idx] = ~0ull;
        gIdx[idx] = -1;
        gLab[idx] = -2;
    }
}

// contention-free rank: one block per subject, ballot-prefix over all rows.
// writes pos[row] for rows of this subject, and final count into writePtr[s].
__global__ void k_rank(const int* __restrict__ sbjv, int* __restrict__ pos,
                       int* __restrict__ writePtr) {
    int s = blockIdx.x;                 // 0..15
    int tid = threadIdx.x;              // 256
    int lane = tid & 63, w = tid >> 6;
    __shared__ int wsum[4];
    __shared__ int carry;
    if (tid == 0) carry = s * PADS;
    __syncthreads();
    for (int base = 0; base < N; base += 256) {
        int row = base + tid;
        bool m = (sbjv[row] == s);
        u64 bal = __ballot(m);
        int prefix = __popcll(bal & ((1ull << lane) - 1ull));
        if (lane == 0) wsum[w] = __popcll(bal);
        __syncthreads();
        int wpre = 0;
        #pragma unroll
        for (int ww = 0; ww < 4; ++ww) if (ww < w) wpre += wsum[ww];
        int total = wsum[0] + wsum[1] + wsum[2] + wsum[3];
        if (m) pos[row] = carry + wpre + prefix;
        __syncthreads();
        if (tid == 0) carry += total;
        __syncthreads();
    }
    if (tid == 0) writePtr[s] = carry;   // == s*PADS + count(s)
}

// gather rows by subject into precomputed slots; fp32 -> bf16; fold in sq-norm
__global__ void k_scatter(const float* __restrict__ emb, const int* __restrict__ labels,
                          const int* __restrict__ sbjv, const int* __restrict__ pos,
                          unsigned short* __restrict__ gH, int* __restrict__ gIdx,
                          int* __restrict__ gLab, float* __restrict__ gSq) {
    int wave = threadIdx.x >> 6;
    int lane = threadIdx.x & 63;
    int row = blockIdx.x * 4 + wave;
    const float4* e4 = (const float4*)(emb + (size_t)row * D);
    float4 v = e4[lane];
    float s = v.x * v.x + v.y * v.y + v.z * v.z + v.w * v.w;
    #pragma unroll
    for (int o = 32; o; o >>= 1) s += __shfl_xor(s, o, 64);
    int p = pos[row];                    // wave-uniform load, no atomics
    us4 h;
    h.x = f2bf(v.x); h.y = f2bf(v.y); h.z = f2bf(v.z); h.w = f2bf(v.w);
    *(us4*)(gH + (size_t)p * D + lane * 4) = h;
    if (lane == 0) { gIdx[p] = row; gLab[p] = labels[row]; gSq[p] = s; }
}

// block-diagonal bf16 MFMA GEMM + fused hardest-pos/neg mining
__global__ __launch_bounds__(256) void k_mine(
        const unsigned short* __restrict__ gH, const int* __restrict__ gIdx,
        const int* __restrict__ gLab, const float* __restrict__ gSq,
        const int* __restrict__ writePtr,
        u64* __restrict__ posP, u64* __restrict__ negP) {
    __shared__ unsigned short As[128 * 32];   // 8 KB, row-major [row][k] (BK=32)
    __shared__ unsigned short Bs[128 * 32];   // 8 KB
    __shared__ int labA[128], idxA[128], labB[128], idxB[128];
    __shared__ float sqA[128], sqB[128];

    int s  = blockIdx.x / (TPS * TPS);
    int t  = blockIdx.x % (TPS * TPS);
    int rt = t / TPS, ct = t % TPS;
    int base = s * PADS;
    int cntS = writePtr[s] - base;
    if (rt * 128 >= cntS || ct * 128 >= cntS) return;   // uniform: whole tile is pad
    int i0 = base + rt * 128;
    int j0 = base + ct * 128;

    int tid  = threadIdx.x;
    int lane = tid & 63, w = tid >> 6;
    int quad = lane >> 4, l15 = lane & 15;
    int wRow = (w & 1) * 64, wCol = (w >> 1) * 64;   // wave tile 64x64

    if (tid < 128) {
        labA[tid] = gLab[i0 + tid]; idxA[tid] = gIdx[i0 + tid]; sqA[tid] = gSq[i0 + tid];
    } else {
        int c = tid - 128;
        labB[c] = gLab[j0 + c]; idxB[c] = gIdx[j0 + c]; sqB[c] = gSq[j0 + c];
    }

    f32x4 acc[4][4];
    #pragma unroll
    for (int mt = 0; mt < 4; ++mt)
        #pragma unroll
        for (int nt = 0; nt < 4; ++nt) {
            f32x4 z = {0.f, 0.f, 0.f, 0.f};
            acc[mt][nt] = z;
        }

    for (int kb = 0; kb < 8; ++kb) {          // K = 8 * 32
        int k0 = kb * 32;
        #pragma unroll
        for (int rr = 0; rr < 2; ++rr) {      // 128 rows x 64B = 2 rounds of 256x16B
            int f = rr * 256 + tid;
            int row = f >> 2, seg = f & 3;
            unsigned short* ldst = (unsigned short*)&As[0] + (size_t)(rr * 256 + w * 64) * 8;
            gl_lds16(gH + (size_t)(i0 + row) * D + k0 + seg * 8, ldst);
            unsigned short* ldstB = (unsigned short*)&Bs[0] + (size_t)(rr * 256 + w * 64) * 8;
            gl_lds16(gH + (size_t)(j0 + row) * D + k0 + seg * 8, ldstB);
        }
        __syncthreads();
        short8 a[4], b[4];
        int koff = quad * 8;
        #pragma unroll
        for (int mt = 0; mt < 4; ++mt)
            a[mt] = *(const short8*)(As + (wRow + mt * 16 + l15) * 32 + koff);
        #pragma unroll
        for (int nt = 0; nt < 4; ++nt)
            b[nt] = *(const short8*)(Bs + (wCol + nt * 16 + l15) * 32 + koff);
        #pragma unroll
        for (int mt = 0; mt < 4; ++mt)
            #pragma unroll
            for (int nt = 0; nt < 4; ++nt)
                acc[mt][nt] = __builtin_amdgcn_mfma_f32_16x16x32_bf16(
                    a[mt], b[nt], acc[mt][nt], 0, 0, 0);
        __syncthreads();
    }

    // ---- mining epilogue: C layout col = lane&15, row = quad*4 + reg ----
    #pragma unroll
    for (int mt = 0; mt < 4; ++mt) {
        u64 bp[4], bn[4];
        int rloc[4], labr[4], idxr[4];
        float sqr[4];
        #pragma unroll
        for (int rg = 0; rg < 4; ++rg) {
            int r = wRow + mt * 16 + quad * 4 + rg;
            rloc[rg] = r; labr[rg] = labA[r]; idxr[rg] = idxA[r]; sqr[rg] = sqA[r];
            bp[rg] = 0ull; bn[rg] = ~0ull;
        }
        #pragma unroll
        for (int nt = 0; nt < 4; ++nt) {
            int c = wCol + nt * 16 + l15;
            int labc = labB[c], idxc = idxB[c];
            float sqc = sqB[c];
            f32x4 v = acc[mt][nt];
            #pragma unroll
            for (int rg = 0; rg < 4; ++rg) {
                float d2 = fmaxf(sqr[rg] + sqc - 2.0f * v[rg], 0.0f);
                u64 db = ((u64)__float_as_uint(d2)) << 32;
                if (labc == labr[rg] && idxc != idxr[rg] && idxc >= 0) {
                    u64 pk = db | (u64)(unsigned)(~(unsigned)idxc);
                    if (pk > bp[rg]) bp[rg] = pk;
                }
                if (labc != labr[rg] && idxc >= 0) {
                    u64 nk = db | (u64)(unsigned)idxc;
                    if (nk < bn[rg]) bn[rg] = nk;
                }
            }
        }
        #pragma unroll
        for (int o = 1; o < 16; o <<= 1) {
            #pragma unroll
            for (int rg = 0; rg < 4; ++rg) {
                u64 pp = __shfl_xor(bp[rg], o, 64);
                if (pp > bp[rg]) bp[rg] = pp;
                u64 qq = __shfl_xor(bn[rg], o, 64);
                if (qq < bn[rg]) bn[rg] = qq;
            }
        }
        if (l15 == 0) {
            #pragma unroll
            for (int rg = 0; rg < 4; ++rg) {
                if (bp[rg]) atomicMax(&posP[i0 + rloc[rg]], bp[rg]);
                if (bn[rg] != ~0ull) atomicMin(&negP[i0 + rloc[rg]], bn[rg]);
            }
        }
    }
}

// per-row hinge recompute in fp32; NO global atomics — per-row float2 store
__global__ void k_fin(const float* __restrict__ emb, const int* __restrict__ gIdx,
                      const u64* __restrict__ posP, const u64* __restrict__ negP,
                      float2* __restrict__ perOut) {
    int wave = threadIdx.x >> 6;
    int lane = threadIdx.x & 63;
    int r = blockIdx.x * 4 + wave;
    int i = gIdx[r];
    u64 p = posP[r];
    u64 nn = negP[r];
    bool valid = (i >= 0) && (p != 0ull) && (nn != ~0ull);
    if (!valid) {                         // wave-uniform
        if (lane == 0) perOut[r] = make_float2(0.0f, 0.0f);
        return;
    }
    int hp = (int)(~(unsigned)(p & 0xffffffffull));
    int hn = (int)(unsigned)(nn & 0xffffffffull);
    const float4* a  = (const float4*)(emb + (size_t)i  * D);
    const float4* bp = (const float4*)(emb + (size_t)hp * D);
    const float4* bn = (const float4*)(emb + (size_t)hn * D);
    float4 va = a[lane], vp = bp[lane], vn = bn[lane];
    float x, sp = 0.0f, sn = 0.0f;
    x = va.x - vp.x + EPS; sp += x * x;
    x = va.y - vp.y + EPS; sp += x * x;
    x = va.z - vp.z + EPS; sp += x * x;
    x = va.w - vp.w + EPS; sp += x * x;
    x = va.x - vn.x + EPS; sn += x * x;
    x = va.y - vn.y + EPS; sn += x * x;
    x = va.z - vn.z + EPS; sn += x * x;
    x = va.w - vn.w + EPS; sn += x * x;
    #pragma unroll
    for (int o = 32; o; o >>= 1) {
        sp += __shfl_xor(sp, o, 64);
        sn += __shfl_xor(sn, o, 64);
    }
    if (lane == 0) {
        float per = fmaxf(sqrtf(sp) - sqrtf(sn) + MARGIN, 0.0f);
        perOut[r] = make_float2(per, 1.0f);
    }
}

// single-block tree reduction over perOut, writes final scalar
__global__ void k_reduce(const float4* __restrict__ perOut, float* __restrict__ out) {
    int tid = threadIdx.x;
    float s = 0.0f, c = 0.0f;
    for (int i = tid; i < GN / 2; i += 256) {   // each float4 = 2 (per, valid) pairs
        float4 v = perOut[i];
        s += v.x + v.z;
        c += v.y + v.w;
    }
    #pragma unroll
    for (int o = 32; o; o >>= 1) {
        s += __shfl_xor(s, o, 64);
        c += __shfl_xor(c, o, 64);
    }
    __shared__ float ss[4], sc[4];
    int w = tid >> 6, lane = tid & 63;
    if (lane == 0) { ss[w] = s; sc[w] = c; }
    __syncthreads();
    if (tid == 0) {
        float S = ss[0] + ss[1] + ss[2] + ss[3];
        float C = sc[0] + sc[1] + sc[2] + sc[3];
        out[0] = S / (C < 1.0f ? 1.0f : C);
    }
}

extern "C" void kernel_launch(void* const* d_in, const int* in_sizes, int n_in,
                              void* d_out, int out_size, void* d_ws, size_t ws_size,
                              hipStream_t stream) {
    const float* emb  = (const float*)d_in[0];
    const int* labels = (const int*)d_in[1];
    const int* sbjv   = (const int*)d_in[2];
    float* out = (float*)d_out;

    char* ws = (char*)d_ws;
    unsigned short* gH = (unsigned short*)ws;                 // GN*D*2 = 6291456 B
    u64* posP = (u64*)(ws + 6291456);                         // GN*8 = 98304
    u64* negP = (u64*)(ws + 6291456 + 98304);
    int* gIdx = (int*)(ws + 6291456 + 196608);                // GN*4 = 49152
    int* gLab = (int*)(ws + 6291456 + 245760);
    float* gSq = (float*)(ws + 6291456 + 294912);
    int* writePtr = (int*)(ws + 6291456 + 344064);            // 64 B
    float2* perOut = (float2*)(ws + 6291456 + 344064 + 64);   // GN*8 = 98304
    int* pos = (int*)(ws + 6291456 + 344064 + 64 + 98304);    // N*4 = 32768

    k_init<<<(GN + 255) / 256, 256, 0, stream>>>(posP, negP, gIdx, gLab);
    k_rank<<<NSUBJ, 256, 0, stream>>>(sbjv, pos, writePtr);
    k_scatter<<<N / 4, 256, 0, stream>>>(emb, labels, sbjv, pos, gH, gIdx, gLab, gSq);
    k_mine<<<NSUBJ * TPS * TPS, 256, 0, stream>>>(gH, gIdx, gLab, gSq, writePtr, posP, negP);
    k_fin<<<GN / 4, 256, 0, stream>>>(emb, gIdx, posP, negP, perOut);
    k_reduce<<<1, 256, 0, stream>>>((const float4*)perOut, out);
}